// Round 3
// baseline (5201.940 us; speedup 1.0000x reference)
//
#include <hip/hip_runtime.h>
#include <hip/hip_cooperative_groups.h>

namespace cg = cooperative_groups;

static constexpr int B_ = 8;
static constexpr int N_ = 16384;
static constexpr int D_ = 256;
static constexpr int L_ = 64;

// fused-kernel geometry: 256 WGs x 512 threads, 1 WG/CU, 1 point/thread
static constexpr int TPB = 512;
static constexpr int LF4 = 16;        // dims 0..63 live in LDS (16 float4)
static constexpr int RF4 = 64 - LF4;  // dims 64..255 live in VGPRs (48 float4)

// ---------------------------------------------------------------------------
// Fused FPS scan + witness, data-resident. LDS: 128 KB point slab + 1 KB
// landmark row + reduce scratch = ~133 KB -> exactly 1 WG/CU. Coop grid 256
// only requires maxActiveBlocks >= 1. launch_bounds(512,2) caps VGPR at 256
// (8 waves/WG = 2 waves/SIMD), so the WG is always schedulable.
// Scan FMA order (d0..d3 accumulators, k ascending) is bit-identical to the
// round-1 kernel that validated with absmax 0.
// ---------------------------------------------------------------------------
__global__ void __launch_bounds__(TPB, 2)
fps_fused_kernel(const float* __restrict__ emb, const float* __restrict__ csp,
                 float* __restrict__ xn,
                 float* __restrict__ pval, int* __restrict__ pidx,
                 unsigned char* __restrict__ adj)
{
    cg::grid_group grid = cg::this_grid();
    const int wg  = blockIdx.x;        // 0..255
    const int b   = wg >> 5;           // batch (32 WGs per batch)
    const int wib = wg & 31;
    const int tid = threadIdx.x;
    const int n   = (wib << 9) + tid;  // my point
    const float c = fabsf(csp[0]);

    // zero adjacency every call (ws poisoned 0xAA once, never re-poisoned)
    const int gid = wg * TPB + tid;
    if (gid < B_ * L_ * L_) adj[gid] = 0;

    __shared__ float4 lds_pts[LF4 * TPB];   // 131072 B, [k][tid] 2-way-free
    __shared__ float  lmbuf[D_];            // staged landmark row (1 KB)
    __shared__ float  rval[TPB];
    __shared__ int    ridx[TPB];
    __shared__ int    lmhist[L_];
    __shared__ int    s_next;

    const float4* __restrict__ pt = (const float4*)(emb + (size_t)(b * N_ + n) * D_);

    // resident load: 16 float4 -> LDS, 48 float4 -> VGPRs; norm on the fly
    float4 p[RF4];
    float s0 = 0.f, s1 = 0.f, s2 = 0.f, s3 = 0.f;
    #pragma unroll
    for (int k = 0; k < LF4; ++k) {
        float4 v = pt[k];
        lds_pts[k * TPB + tid] = v;
        s0 = fmaf(v.x, v.x, s0); s1 = fmaf(v.y, v.y, s1);
        s2 = fmaf(v.z, v.z, s2); s3 = fmaf(v.w, v.w, s3);
    }
    #pragma unroll
    for (int k = 0; k < RF4; ++k) {
        float4 v = pt[LF4 + k];
        p[k] = v;
        s0 = fmaf(v.x, v.x, s0); s1 = fmaf(v.y, v.y, s1);
        s2 = fmaf(v.z, v.z, s2); s3 = fmaf(v.w, v.w, s3);
    }
    const float my_xn = (s0 + s1) + (s2 + s3);
    xn[b * N_ + n] = my_xn;
    if (tid == 0) lmhist[0] = 0;          // seed landmark = index 0

    float min_d = __builtin_inff();
    int lmIdx = 0;

    grid.sync();   // xn visible grid-wide

    int parity = 0;
    for (int s = 1; s < L_; ++s) {
        const int lmU = __builtin_amdgcn_readfirstlane(lmIdx);
        // stage landmark row into LDS (coalesced, 256 floats)
        if (tid < D_) lmbuf[tid] = emb[(size_t)(b * N_ + lmU) * D_ + tid];
        const float lmn = xn[b * N_ + lmU];
        __syncthreads();

        const float4* __restrict__ w4 = (const float4*)lmbuf;
        float d0 = 0.f, d1 = 0.f, d2 = 0.f, d3 = 0.f;
        #pragma unroll
        for (int k = 0; k < LF4; ++k) {
            float4 v = lds_pts[k * TPB + tid];
            float4 w = w4[k];
            d0 = fmaf(v.x, w.x, d0); d1 = fmaf(v.y, w.y, d1);
            d2 = fmaf(v.z, w.z, d2); d3 = fmaf(v.w, w.w, d3);
        }
        #pragma unroll
        for (int k = 0; k < RF4; ++k) {
            float4 v = p[k];
            float4 w = w4[LF4 + k];
            d0 = fmaf(v.x, w.x, d0); d1 = fmaf(v.y, w.y, d1);
            d2 = fmaf(v.z, w.z, d2); d3 = fmaf(v.w, w.w, d3);
        }
        const float dot  = (d0 + d1) + (d2 + d3);
        const float diff = fmaxf(my_xn + lmn - 2.f * dot, 1e-10f);
        const float fac  = fmaxf(1.f + c * my_xn + c * lmn, 1e-6f);
        const float d    = sqrtf(diff) * sqrtf(fac);
        min_d = fminf(min_d, d);

        // block argmax (512) of (min_d, n); ties -> lower index
        rval[tid] = min_d; ridx[tid] = n;
        __syncthreads();
        #pragma unroll
        for (int st = 256; st >= 1; st >>= 1) {
            if (tid < st) {
                float ov = rval[tid + st]; int oi = ridx[tid + st];
                float mv = rval[tid];      int mi = ridx[tid];
                if (ov > mv || (ov == mv && oi < mi)) { rval[tid] = ov; ridx[tid] = oi; }
            }
            __syncthreads();
        }
        if (tid == 0) {
            pval[(parity * B_ + b) * 32 + wib] = rval[0];
            pidx[(parity * B_ + b) * 32 + wib] = ridx[0];
        }
        grid.sync();

        // reduce this batch's 32 WG candidates (lanes 0..31 of wave 0)
        if (tid < 32) {
            float v = pval[(parity * B_ + b) * 32 + tid];
            int   i = pidx[(parity * B_ + b) * 32 + tid];
            #pragma unroll
            for (int off = 16; off >= 1; off >>= 1) {
                float ov = __shfl_down(v, off);
                int   oi = __shfl_down(i, off);
                if (ov > v || (ov == v && oi < i)) { v = ov; i = oi; }
            }
            if (tid == 0) s_next = i;
        }
        __syncthreads();
        lmIdx = s_next;
        if (tid == 0) lmhist[s] = lmIdx;
        parity ^= 1;
    }
    __syncthreads();   // publish lmhist[63]

    // ---- fused witness: dot resident point with all 64 landmarks.
    // ascending scan + strict '<' == jax.lax.top_k stability (validated r1).
    float b1v = __builtin_inff(), b2v = __builtin_inff();
    int b1i = 0, b2i = 0;
    #pragma unroll 1
    for (int lm = 0; lm < L_; ++lm) {
        const int li = __builtin_amdgcn_readfirstlane(lmhist[lm]);
        __syncthreads();                    // previous lmbuf reads done
        if (tid < D_) lmbuf[tid] = emb[(size_t)(b * N_ + li) * D_ + tid];
        const float ln = xn[b * N_ + li];
        __syncthreads();                    // staged

        const float4* __restrict__ w4 = (const float4*)lmbuf;
        float d0 = 0.f, d1 = 0.f, d2 = 0.f, d3 = 0.f;
        #pragma unroll
        for (int k = 0; k < LF4; ++k) {
            float4 v = lds_pts[k * TPB + tid];
            float4 w = w4[k];
            d0 = fmaf(v.x, w.x, d0); d1 = fmaf(v.y, w.y, d1);
            d2 = fmaf(v.z, w.z, d2); d3 = fmaf(v.w, w.w, d3);
        }
        #pragma unroll
        for (int k = 0; k < RF4; ++k) {
            float4 v = p[k];
            float4 w = w4[LF4 + k];
            d0 = fmaf(v.x, w.x, d0); d1 = fmaf(v.y, w.y, d1);
            d2 = fmaf(v.z, w.z, d2); d3 = fmaf(v.w, w.w, d3);
        }
        const float dot  = (d0 + d1) + (d2 + d3);
        const float diff = fmaxf(my_xn + ln - 2.f * dot, 1e-10f);
        const float fac  = fmaxf(1.f + c * my_xn + c * ln, 1e-6f);
        const float d    = sqrtf(diff) * sqrtf(fac);
        if (d < b1v)      { b2v = b1v; b2i = b1i; b1v = d; b1i = lm; }
        else if (d < b2v) { b2v = d; b2i = lm; }
    }
    {
        const int lo = min(b1i, b2i), hi = max(b1i, b2i);
        adj[(b * 64 + lo) * 64 + hi] = 1;   // same-value byte races: benign
    }
}

// ===========================================================================
// FALLBACK PATH — the exact round-1 kernels that passed (absmax 0, 5.2 ms).
// Used only if the fused kernel cannot schedule (occupancy query == 0).
// ===========================================================================
__global__ void __launch_bounds__(256)
fps_kernel(const float* __restrict__ emb, const float* __restrict__ csp,
           float* __restrict__ xn, int* __restrict__ lm_idx,
           float* __restrict__ pval, int* __restrict__ pidx,
           unsigned char* __restrict__ adj)
{
    cg::grid_group grid = cg::this_grid();
    const int wg  = blockIdx.x;
    const int b   = wg >> 6;
    const int wib = wg & 63;
    const int tid = threadIdx.x;
    const int n   = (wib << 8) + tid;
    const float c = fabsf(csp[0]);

    const int gid = wg * 256 + tid;
    if (gid < B_ * L_ * L_) adj[gid] = 0;

    const float4* pt = (const float4*)(emb + (size_t)(b * N_ + n) * D_);

    float s0 = 0.f, s1 = 0.f, s2 = 0.f, s3 = 0.f;
    #pragma unroll 8
    for (int k = 0; k < D_ / 4; ++k) {
        float4 v = pt[k];
        s0 = fmaf(v.x, v.x, s0); s1 = fmaf(v.y, v.y, s1);
        s2 = fmaf(v.z, v.z, s2); s3 = fmaf(v.w, v.w, s3);
    }
    const float my_xn = (s0 + s1) + (s2 + s3);
    xn[b * N_ + n] = my_xn;

    __shared__ __align__(16) float lmbuf[D_];
    __shared__ float rval[256];
    __shared__ int   ridx[256];
    __shared__ int   s_next;

    float min_d = __builtin_inff();
    int lmIdx = 0;
    if (wib == 0 && tid == 0) lm_idx[b * L_] = 0;

    grid.sync();

    int parity = 0;
    for (int s = 1; s < L_; ++s) {
        lmbuf[tid] = emb[(size_t)(b * N_ + lmIdx) * D_ + tid];
        const float lmn = xn[b * N_ + lmIdx];
        __syncthreads();

        const float4* lmv4 = (const float4*)lmbuf;
        float d0 = 0.f, d1 = 0.f, d2 = 0.f, d3 = 0.f;
        #pragma unroll 8
        for (int k = 0; k < D_ / 4; ++k) {
            float4 v = pt[k];
            float4 w = lmv4[k];
            d0 = fmaf(v.x, w.x, d0); d1 = fmaf(v.y, w.y, d1);
            d2 = fmaf(v.z, w.z, d2); d3 = fmaf(v.w, w.w, d3);
        }
        const float dot  = (d0 + d1) + (d2 + d3);
        const float diff = fmaxf(my_xn + lmn - 2.f * dot, 1e-10f);
        const float fac  = fmaxf(1.f + c * my_xn + c * lmn, 1e-6f);
        const float d    = sqrtf(diff) * sqrtf(fac);
        min_d = fminf(min_d, d);

        rval[tid] = min_d; ridx[tid] = n;
        __syncthreads();
        #pragma unroll
        for (int st = 128; st >= 1; st >>= 1) {
            if (tid < st) {
                float ov = rval[tid + st]; int oi = ridx[tid + st];
                float mv = rval[tid];      int mi = ridx[tid];
                if (ov > mv || (ov == mv && oi < mi)) { rval[tid] = ov; ridx[tid] = oi; }
            }
            __syncthreads();
        }
        if (tid == 0) {
            pval[(parity * B_ + b) * 64 + wib] = rval[0];
            pidx[(parity * B_ + b) * 64 + wib] = ridx[0];
        }
        grid.sync();

        if (tid < 64) {
            float v = pval[(parity * B_ + b) * 64 + tid];
            int   i = pidx[(parity * B_ + b) * 64 + tid];
            #pragma unroll
            for (int off = 32; off >= 1; off >>= 1) {
                float ov = __shfl_down(v, off);
                int   oi = __shfl_down(i, off);
                if (ov > v || (ov == v && oi < i)) { v = ov; i = oi; }
            }
            if (tid == 0) s_next = i;
        }
        __syncthreads();
        lmIdx = s_next;
        if (wib == 0 && tid == 0) lm_idx[b * L_ + s] = lmIdx;
        parity ^= 1;
    }
}

__global__ void __launch_bounds__(256)
witness_kernel(const float* __restrict__ emb, const float* __restrict__ csp,
               const float* __restrict__ xn, const int* __restrict__ lm_idx,
               unsigned char* __restrict__ adj)
{
    const int wg  = blockIdx.x;
    const int b   = wg >> 5;
    const int blk = wg & 31;
    const int tid = threadIdx.x;
    const float c = fabsf(csp[0]);

    __shared__ __align__(16) float lmv[32 * 256];
    __shared__ float lmn_s[64];
    __shared__ int   lidx_s[64];

    if (tid < 64) {
        int li = lm_idx[b * 64 + tid];
        lidx_s[tid] = li;
        lmn_s[tid]  = xn[b * N_ + li];
    }
    __syncthreads();

    const int p0 = blk * 512 + tid;
    const float mxn0 = xn[b * N_ + p0];
    const float mxn1 = xn[b * N_ + p0 + 256];
    const float4* ptA = (const float4*)(emb + (size_t)(b * N_ + p0) * D_);
    const float4* ptB = (const float4*)(emb + (size_t)(b * N_ + p0 + 256) * D_);

    float b1v0 = __builtin_inff(), b2v0 = __builtin_inff();
    float b1v1 = __builtin_inff(), b2v1 = __builtin_inff();
    int b1i0 = 0, b2i0 = 0, b1i1 = 0, b2i1 = 0;

    for (int ch = 0; ch < 2; ++ch) {
        __syncthreads();
        #pragma unroll
        for (int r = 0; r < 32; ++r) {
            lmv[r * 256 + tid] = emb[(size_t)(b * N_ + lidx_s[ch * 32 + r]) * D_ + tid];
        }
        __syncthreads();

        float acc0[32], acc1[32];
        #pragma unroll
        for (int j = 0; j < 32; ++j) { acc0[j] = 0.f; acc1[j] = 0.f; }

        #pragma unroll 2
        for (int k = 0; k < 64; ++k) {
            float4 pA = ptA[k];
            float4 pB = ptB[k];
            #pragma unroll
            for (int j = 0; j < 32; ++j) {
                float4 w = *(const float4*)(&lmv[j * 256 + 4 * k]);
                acc0[j] = fmaf(pA.x, w.x, fmaf(pA.y, w.y, fmaf(pA.z, w.z, fmaf(pA.w, w.w, acc0[j]))));
                acc1[j] = fmaf(pB.x, w.x, fmaf(pB.y, w.y, fmaf(pB.z, w.z, fmaf(pB.w, w.w, acc1[j]))));
            }
        }

        #pragma unroll
        for (int j = 0; j < 32; ++j) {
            const int lm = ch * 32 + j;
            const float ln = lmn_s[lm];
            {
                float diff = fmaxf(mxn0 + ln - 2.f * acc0[j], 1e-10f);
                float fac  = fmaxf(1.f + c * mxn0 + c * ln, 1e-6f);
                float d = sqrtf(diff) * sqrtf(fac);
                if (d < b1v0)      { b2v0 = b1v0; b2i0 = b1i0; b1v0 = d; b1i0 = lm; }
                else if (d < b2v0) { b2v0 = d; b2i0 = lm; }
            }
            {
                float diff = fmaxf(mxn1 + ln - 2.f * acc1[j], 1e-10f);
                float fac  = fmaxf(1.f + c * mxn1 + c * ln, 1e-6f);
                float d = sqrtf(diff) * sqrtf(fac);
                if (d < b1v1)      { b2v1 = b1v1; b2i1 = b1i1; b1v1 = d; b1i1 = lm; }
                else if (d < b2v1) { b2v1 = d; b2i1 = lm; }
            }
        }
    }

    {
        int lo = min(b1i0, b2i0), hi = max(b1i0, b2i0);
        adj[(b * 64 + lo) * 64 + hi] = 1;
    }
    {
        int lo = min(b1i1, b2i1), hi = max(b1i1, b2i1);
        adj[(b * 64 + lo) * 64 + hi] = 1;
    }
}

// ---------------------------------------------------------------------------
// Finalize: symmetrize, min-label propagation (64 synchronous iters), betas.
// ---------------------------------------------------------------------------
__global__ void __launch_bounds__(64)
finalize_kernel(const unsigned char* __restrict__ adj, float* __restrict__ out)
{
    const int b = blockIdx.x;
    const int t = threadIdx.x;
    __shared__ int labels[64];

    unsigned long long m = 0ull;
    for (int j = 0; j < 64; ++j) {
        if (adj[(b * 64 + t) * 64 + j] | adj[(b * 64 + j) * 64 + t])
            m |= (1ull << j);
    }
    labels[t] = t;
    __syncthreads();

    for (int it = 0; it < 64; ++it) {
        int mn = labels[t];
        unsigned long long mm = m;
        while (mm) {
            int j = __ffsll(mm) - 1;
            int lj = labels[j];
            mn = mn < lj ? mn : lj;
            mm &= mm - 1;
        }
        __syncthreads();
        labels[t] = mn;
        __syncthreads();
    }

    unsigned long long hi_mask = (t < 63) ? (~0ull << (t + 1)) : 0ull;
    int myedges = __popcll(m & hi_mask);
    int mycomp  = (labels[t] == t) ? 1 : 0;

    for (int off = 32; off >= 1; off >>= 1) {
        myedges += __shfl_down(myedges, off);
        mycomp  += __shfl_down(mycomp, off);
    }
    if (t == 0) {
        float beta0 = (float)mycomp;
        float beta1 = (float)(myedges - (64 - mycomp));
        out[b]      = beta0;
        out[8 + b]  = beta1;
        out[16 + b] = beta0 / 64.f;
        out[24 + b] = (beta1 > 3.f) ? 1.f : 0.f;
    }
}

// ---------------------------------------------------------------------------
extern "C" void kernel_launch(void* const* d_in, const int* in_sizes, int n_in,
                              void* d_out, int out_size, void* d_ws, size_t ws_size,
                              hipStream_t stream)
{
    const float* emb = (const float*)d_in[0];
    const float* cs  = (const float*)d_in[1];
    float* out = (float*)d_out;

    char* ws = (char*)d_ws;
    float*         xn   = (float*)(ws);                  // 524288 B
    int*           lmi  = (int*)  (ws + 524288);         // 2048 B (pad 4096)
    float*         pval = (float*)(ws + 528384);         // 4096 B
    int*           pidx = (int*)  (ws + 532480);         // 4096 B
    unsigned char* adj  = (unsigned char*)(ws + 536576); // 32768 B

    // host-side occupancy probe: deterministic, no stream interaction,
    // graph-capture-safe. Decides fused vs fallback identically every call.
    int nb = 0;
    hipError_t qe = hipOccupancyMaxActiveBlocksPerMultiprocessor(
        &nb, fps_fused_kernel, TPB, 0);
    const bool use_fused = (qe == hipSuccess && nb >= 1);

    if (use_fused) {
        void* args[] = { (void*)&emb, (void*)&cs, (void*)&xn,
                         (void*)&pval, (void*)&pidx, (void*)&adj };
        hipLaunchCooperativeKernel((void*)fps_fused_kernel, dim3(256), dim3(TPB),
                                   args, 0, stream);
    } else {
        void* args[] = { (void*)&emb, (void*)&cs, (void*)&xn, (void*)&lmi,
                         (void*)&pval, (void*)&pidx, (void*)&adj };
        hipLaunchCooperativeKernel((void*)fps_kernel, dim3(512), dim3(256),
                                   args, 0, stream);
        hipLaunchKernelGGL(witness_kernel, dim3(B_ * 32), dim3(256), 0, stream,
                           emb, cs, xn, lmi, adj);
    }
    hipLaunchKernelGGL(finalize_kernel, dim3(B_), dim3(64), 0, stream,
                       adj, out);
}

// Round 4
// 5188.850 us; speedup vs baseline: 1.0025x; 1.0025x over previous
//
#include <hip/hip_runtime.h>
#include <hip/hip_cooperative_groups.h>

namespace cg = cooperative_groups;

static constexpr int B_ = 8;
static constexpr int N_ = 16384;
static constexpr int D_ = 256;
static constexpr int L_ = 64;

static constexpr int TPB = 512;       // 256 WGs x 512 thr, 1 WG/CU, 1 point/thread
static constexpr int LF4 = 16;        // dims 0..63 in LDS
static constexpr int RF4 = 48;        // dims 64..255 in VGPRs

// ---------------------------------------------------------------------------
// init: zero the step-indexed sync slots + adjacency words (16 KB) every call
// (ws is poisoned once and never re-poisoned between graph replays).
// Stream order guarantees visibility to the main kernel.
// ---------------------------------------------------------------------------
__global__ void __launch_bounds__(1024)
init_kernel(unsigned int* __restrict__ z)
{
    const int t = threadIdx.x;
    #pragma unroll
    for (int k = 0; k < 4; ++k) z[k * 1024 + t] = 0u;
}

// ---------------------------------------------------------------------------
// Fused FPS scan + witness + finalize. Cooperative launch ONLY for the
// co-residency guarantee (no grid.sync inside). Per-batch lock-free barriers:
//   per step: block argmax -> atomicMax(packed u64) -> fence -> arrival count;
//   last of 32 WGs publishes winner to flag[s]; others spin (RMW loads).
// Packed key (bits(min_d)<<32)|(0xFFFFFFFF-n): max == (max d, tie lowest n).
// All FMA accumulation orders bit-identical to the r3-validated kernel.
// ---------------------------------------------------------------------------
__global__ void __launch_bounds__(TPB, 2)
fps_all_kernel(const float* __restrict__ emb, const float* __restrict__ csp,
               float* __restrict__ xn,
               unsigned long long* __restrict__ slot,
               unsigned long long* __restrict__ flag,
               unsigned int* __restrict__ cnt,
               unsigned int* __restrict__ gadj,
               float* __restrict__ out)
{
    const int wg  = blockIdx.x;        // 0..255
    const int b   = wg >> 5;           // batch (32 WGs/batch)
    const int wib = wg & 31;
    const int tid = threadIdx.x;
    const int n   = (wib << 9) + tid;  // my point
    const float c = fabsf(csp[0]);

    __shared__ float4 slab[LF4 * TPB];          // 128 KB resident slice
    __shared__ __align__(16) float lmbuf[D_];   // staged landmark row
    __shared__ float wval[8];
    __shared__ int   widx[8];
    __shared__ int   s_next;
    __shared__ int   s_lead;
    __shared__ unsigned int lmask[128];         // 64x64 edge bitmask
    __shared__ int   labels[64];

    if (tid < 128) lmask[tid] = 0u;

    const float4* __restrict__ pt = (const float4*)(emb + (size_t)(b * N_ + n) * D_);

    // resident load + norm (sequential 4-acc over k=0..63, matches r1/r3)
    float4 p[RF4];
    float s0 = 0.f, s1 = 0.f, s2 = 0.f, s3 = 0.f;
    #pragma unroll
    for (int k = 0; k < LF4; ++k) {
        float4 v = pt[k];
        slab[k * TPB + tid] = v;
        s0 = fmaf(v.x, v.x, s0); s1 = fmaf(v.y, v.y, s1);
        s2 = fmaf(v.z, v.z, s2); s3 = fmaf(v.w, v.w, s3);
    }
    #pragma unroll
    for (int k = 0; k < RF4; ++k) {
        float4 v = pt[LF4 + k];
        p[k] = v;
        s0 = fmaf(v.x, v.x, s0); s1 = fmaf(v.y, v.y, s1);
        s2 = fmaf(v.z, v.z, s2); s3 = fmaf(v.w, v.w, s3);
    }
    const float my_xn = (s0 + s1) + (s2 + s3);
    xn[b * N_ + n] = my_xn;   // read by others only after >=1 barrier (release via fence below)

    float min_d = __builtin_inff();
    float b1v = __builtin_inff(), b2v = __builtin_inff();
    int   b1i = 0, b2i = 0;
    int   lm = 0;

    #pragma unroll 1
    for (int s = 1; s <= L_; ++s) {
        // stage row of landmark position s-1 (index lm)
        if (tid < 64)
            ((float4*)lmbuf)[tid] =
                ((const float4*)(emb + (size_t)(b * N_ + lm) * D_))[tid];
        __syncthreads();

        float lmn;
        if (s == 1) {
            // no cross-WG xn visibility yet: compute norm locally (same op order)
            const float4* l4 = (const float4*)lmbuf;
            float t0 = 0.f, t1 = 0.f, t2 = 0.f, t3 = 0.f;
            #pragma unroll
            for (int k = 0; k < 64; ++k) {
                float4 w = l4[k];
                t0 = fmaf(w.x, w.x, t0); t1 = fmaf(w.y, w.y, t1);
                t2 = fmaf(w.z, w.z, t2); t3 = fmaf(w.w, w.w, t3);
            }
            lmn = (t0 + t1) + (t2 + t3);
        } else {
            lmn = xn[b * N_ + lm];   // safe: written before barrier 1, we passed barrier s-1
        }

        const float4* __restrict__ w4 = (const float4*)lmbuf;
        float d0 = 0.f, d1 = 0.f, d2 = 0.f, d3 = 0.f;
        #pragma unroll
        for (int k = 0; k < LF4; ++k) {
            float4 v = slab[k * TPB + tid];
            float4 w = w4[k];
            d0 = fmaf(v.x, w.x, d0); d1 = fmaf(v.y, w.y, d1);
            d2 = fmaf(v.z, w.z, d2); d3 = fmaf(v.w, w.w, d3);
        }
        #pragma unroll
        for (int k = 0; k < RF4; ++k) {
            float4 v = p[k];
            float4 w = w4[LF4 + k];
            d0 = fmaf(v.x, w.x, d0); d1 = fmaf(v.y, w.y, d1);
            d2 = fmaf(v.z, w.z, d2); d3 = fmaf(v.w, w.w, d3);
        }
        const float dot  = (d0 + d1) + (d2 + d3);
        const float diff = fmaxf(my_xn + lmn - 2.f * dot, 1e-10f);
        const float fac  = fmaxf(1.f + c * my_xn + c * lmn, 1e-6f);
        const float d    = sqrtf(diff) * sqrtf(fac);

        // fused witness: landmark POSITION s-1, ascending order, strict '<'
        if (d < b1v)      { b2v = b1v; b2i = b1i; b1v = d; b1i = s - 1; }
        else if (d < b2v) { b2v = d; b2i = s - 1; }

        if (s == L_) break;          // position 63 processed; no more selection

        min_d = fminf(min_d, d);

        // wave argmax (tie -> lower n), then cross-wave among 8 leaders
        float v = min_d; int i = n;
        #pragma unroll
        for (int off = 32; off >= 1; off >>= 1) {
            float ov = __shfl_down(v, off);
            int   oi = __shfl_down(i, off);
            if (ov > v || (ov == v && oi < i)) { v = ov; i = oi; }
        }
        if ((tid & 63) == 0) { wval[tid >> 6] = v; widx[tid >> 6] = i; }
        __syncthreads();
        if (tid < 8) {
            v = wval[tid]; i = widx[tid];
            #pragma unroll
            for (int off = 4; off >= 1; off >>= 1) {
                float ov = __shfl_down(v, off);
                int   oi = __shfl_down(i, off);
                if (ov > v || (ov == v && oi < i)) { v = ov; i = oi; }
            }
        }

        // per-batch lock-free barrier + winner exchange (thread 0 only)
        if (tid == 0) {
            unsigned long long pack =
                ((unsigned long long)__float_as_uint(v) << 32) |
                (unsigned long long)(0xFFFFFFFFu - (unsigned)i);
            unsigned long long* sp = &slot[b * 64 + s];
            atomicMax(sp, pack);
            __threadfence();
            unsigned prev = atomicAdd(&cnt[b * 128 + s], 1u);
            unsigned long long got;
            if (prev == 31u) {                  // last arriver: publish winner
                got = atomicMax(sp, 0ull);      // RMW read of final max
                __threadfence();
                atomicExch(&flag[b * 64 + s], got);
            } else {
                do {
                    got = atomicAdd(&flag[b * 64 + s], 0ull);  // RMW load
                    if (got) break;
                    __builtin_amdgcn_s_sleep(4);
                } while (true);
                __threadfence();                // acquire for subsequent xn reads
            }
            s_next = (int)(0xFFFFFFFFu - (unsigned)(got & 0xFFFFFFFFull));
        }
        __syncthreads();
        lm = s_next;
    }

    // emit my edge (top-2 landmark positions) into LDS bitmask
    {
        const int lo = min(b1i, b2i), hi = max(b1i, b2i);
        const int bitpos = lo * 64 + hi;
        atomicOr(&lmask[bitpos >> 5], 1u << (bitpos & 31));
    }
    __syncthreads();
    if (tid < 128) {
        unsigned w = lmask[tid];
        if (w) atomicOr(&gadj[b * 128 + tid], w);   // device-scope RMW at LLC
    }
    __syncthreads();   // drains the WG's atomics (vmcnt) before arrival

    if (tid == 0) {
        __threadfence();
        unsigned prev = atomicAdd(&cnt[b * 128 + 64], 1u);
        s_lead = (prev == 31u) ? 1 : 0;
    }
    __syncthreads();
    if (!s_lead) return;              // non-leader WGs exit

    // ---- leader WG (last arriver): finalize this batch ----
    __threadfence();
    if (tid < 128) lmask[tid] = atomicOr(&gadj[b * 128 + tid], 0u);  // coherent read
    __syncthreads();

    unsigned long long m = 0ull;
    if (tid < 64) {
        m = ((unsigned long long)lmask[tid * 2 + 1] << 32) | lmask[tid * 2];
        for (int j = 0; j < 64; ++j)           // symmetrize: column bits
            if (lmask[j * 2 + (tid >> 5)] & (1u << (tid & 31))) m |= 1ull << j;
        labels[tid] = tid;
    }
    __syncthreads();

    for (int it = 0; it < 64; ++it) {          // synchronous min-label propagation
        int mn = 0;
        if (tid < 64) {
            mn = labels[tid];
            unsigned long long mm = m;
            while (mm) {
                int j = __ffsll(mm) - 1;
                int lj = labels[j];
                mn = mn < lj ? mn : lj;
                mm &= mm - 1;
            }
        }
        __syncthreads();
        if (tid < 64) labels[tid] = mn;
        __syncthreads();
    }

    if (tid < 64) {
        unsigned long long hi_mask = (tid < 63) ? (~0ull << (tid + 1)) : 0ull;
        int myedges = __popcll(m & hi_mask);
        int mycomp  = (labels[tid] == tid) ? 1 : 0;
        #pragma unroll
        for (int off = 32; off >= 1; off >>= 1) {
            myedges += __shfl_down(myedges, off);
            mycomp  += __shfl_down(mycomp, off);
        }
        if (tid == 0) {
            float beta0 = (float)mycomp;
            float beta1 = (float)(myedges - (64 - mycomp));
            out[b]      = beta0;
            out[8 + b]  = beta1;
            out[16 + b] = beta0 / 64.f;
            out[24 + b] = (beta1 > 3.f) ? 1.f : 0.f;
        }
    }
}

// ===========================================================================
// FALLBACK PATH — round-1 kernels (validated absmax 0), used only if the
// fused kernel cannot schedule.
// ===========================================================================
__global__ void __launch_bounds__(256)
fps_kernel(const float* __restrict__ emb, const float* __restrict__ csp,
           float* __restrict__ xn, int* __restrict__ lm_idx,
           float* __restrict__ pval, int* __restrict__ pidx,
           unsigned char* __restrict__ adj)
{
    cg::grid_group grid = cg::this_grid();
    const int wg  = blockIdx.x;
    const int b   = wg >> 6;
    const int wib = wg & 63;
    const int tid = threadIdx.x;
    const int n   = (wib << 8) + tid;
    const float c = fabsf(csp[0]);

    const int gid = wg * 256 + tid;
    if (gid < B_ * L_ * L_) adj[gid] = 0;

    const float4* pt = (const float4*)(emb + (size_t)(b * N_ + n) * D_);

    float s0 = 0.f, s1 = 0.f, s2 = 0.f, s3 = 0.f;
    #pragma unroll 8
    for (int k = 0; k < D_ / 4; ++k) {
        float4 v = pt[k];
        s0 = fmaf(v.x, v.x, s0); s1 = fmaf(v.y, v.y, s1);
        s2 = fmaf(v.z, v.z, s2); s3 = fmaf(v.w, v.w, s3);
    }
    const float my_xn = (s0 + s1) + (s2 + s3);
    xn[b * N_ + n] = my_xn;

    __shared__ __align__(16) float lmbuf[D_];
    __shared__ float rval[256];
    __shared__ int   ridx[256];
    __shared__ int   s_next;

    float min_d = __builtin_inff();
    int lmIdx = 0;
    if (wib == 0 && tid == 0) lm_idx[b * L_] = 0;

    grid.sync();

    int parity = 0;
    for (int s = 1; s < L_; ++s) {
        lmbuf[tid] = emb[(size_t)(b * N_ + lmIdx) * D_ + tid];
        const float lmn = xn[b * N_ + lmIdx];
        __syncthreads();

        const float4* lmv4 = (const float4*)lmbuf;
        float d0 = 0.f, d1 = 0.f, d2 = 0.f, d3 = 0.f;
        #pragma unroll 8
        for (int k = 0; k < D_ / 4; ++k) {
            float4 v = pt[k];
            float4 w = lmv4[k];
            d0 = fmaf(v.x, w.x, d0); d1 = fmaf(v.y, w.y, d1);
            d2 = fmaf(v.z, w.z, d2); d3 = fmaf(v.w, w.w, d3);
        }
        const float dot  = (d0 + d1) + (d2 + d3);
        const float diff = fmaxf(my_xn + lmn - 2.f * dot, 1e-10f);
        const float fac  = fmaxf(1.f + c * my_xn + c * lmn, 1e-6f);
        const float d    = sqrtf(diff) * sqrtf(fac);
        min_d = fminf(min_d, d);

        rval[tid] = min_d; ridx[tid] = n;
        __syncthreads();
        #pragma unroll
        for (int st = 128; st >= 1; st >>= 1) {
            if (tid < st) {
                float ov = rval[tid + st]; int oi = ridx[tid + st];
                float mv = rval[tid];      int mi = ridx[tid];
                if (ov > mv || (ov == mv && oi < mi)) { rval[tid] = ov; ridx[tid] = oi; }
            }
            __syncthreads();
        }
        if (tid == 0) {
            pval[(parity * B_ + b) * 64 + wib] = rval[0];
            pidx[(parity * B_ + b) * 64 + wib] = ridx[0];
        }
        grid.sync();

        if (tid < 64) {
            float v = pval[(parity * B_ + b) * 64 + tid];
            int   i = pidx[(parity * B_ + b) * 64 + tid];
            #pragma unroll
            for (int off = 32; off >= 1; off >>= 1) {
                float ov = __shfl_down(v, off);
                int   oi = __shfl_down(i, off);
                if (ov > v || (ov == v && oi < i)) { v = ov; i = oi; }
            }
            if (tid == 0) s_next = i;
        }
        __syncthreads();
        lmIdx = s_next;
        if (wib == 0 && tid == 0) lm_idx[b * L_ + s] = lmIdx;
        parity ^= 1;
    }
}

__global__ void __launch_bounds__(256)
witness_kernel(const float* __restrict__ emb, const float* __restrict__ csp,
               const float* __restrict__ xn, const int* __restrict__ lm_idx,
               unsigned char* __restrict__ adj)
{
    const int wg  = blockIdx.x;
    const int b   = wg >> 5;
    const int blk = wg & 31;
    const int tid = threadIdx.x;
    const float c = fabsf(csp[0]);

    __shared__ __align__(16) float lmv[32 * 256];
    __shared__ float lmn_s[64];
    __shared__ int   lidx_s[64];

    if (tid < 64) {
        int li = lm_idx[b * 64 + tid];
        lidx_s[tid] = li;
        lmn_s[tid]  = xn[b * N_ + li];
    }
    __syncthreads();

    const int p0 = blk * 512 + tid;
    const float mxn0 = xn[b * N_ + p0];
    const float mxn1 = xn[b * N_ + p0 + 256];
    const float4* ptA = (const float4*)(emb + (size_t)(b * N_ + p0) * D_);
    const float4* ptB = (const float4*)(emb + (size_t)(b * N_ + p0 + 256) * D_);

    float b1v0 = __builtin_inff(), b2v0 = __builtin_inff();
    float b1v1 = __builtin_inff(), b2v1 = __builtin_inff();
    int b1i0 = 0, b2i0 = 0, b1i1 = 0, b2i1 = 0;

    for (int ch = 0; ch < 2; ++ch) {
        __syncthreads();
        #pragma unroll
        for (int r = 0; r < 32; ++r) {
            lmv[r * 256 + tid] = emb[(size_t)(b * N_ + lidx_s[ch * 32 + r]) * D_ + tid];
        }
        __syncthreads();

        float acc0[32], acc1[32];
        #pragma unroll
        for (int j = 0; j < 32; ++j) { acc0[j] = 0.f; acc1[j] = 0.f; }

        #pragma unroll 2
        for (int k = 0; k < 64; ++k) {
            float4 pA = ptA[k];
            float4 pB = ptB[k];
            #pragma unroll
            for (int j = 0; j < 32; ++j) {
                float4 w = *(const float4*)(&lmv[j * 256 + 4 * k]);
                acc0[j] = fmaf(pA.x, w.x, fmaf(pA.y, w.y, fmaf(pA.z, w.z, fmaf(pA.w, w.w, acc0[j]))));
                acc1[j] = fmaf(pB.x, w.x, fmaf(pB.y, w.y, fmaf(pB.z, w.z, fmaf(pB.w, w.w, acc1[j]))));
            }
        }

        #pragma unroll
        for (int j = 0; j < 32; ++j) {
            const int lm = ch * 32 + j;
            const float ln = lmn_s[lm];
            {
                float diff = fmaxf(mxn0 + ln - 2.f * acc0[j], 1e-10f);
                float fac  = fmaxf(1.f + c * mxn0 + c * ln, 1e-6f);
                float d = sqrtf(diff) * sqrtf(fac);
                if (d < b1v0)      { b2v0 = b1v0; b2i0 = b1i0; b1v0 = d; b1i0 = lm; }
                else if (d < b2v0) { b2v0 = d; b2i0 = lm; }
            }
            {
                float diff = fmaxf(mxn1 + ln - 2.f * acc1[j], 1e-10f);
                float fac  = fmaxf(1.f + c * mxn1 + c * ln, 1e-6f);
                float d = sqrtf(diff) * sqrtf(fac);
                if (d < b1v1)      { b2v1 = b1v1; b2i1 = b1i1; b1v1 = d; b1i1 = lm; }
                else if (d < b2v1) { b2v1 = d; b2i1 = lm; }
            }
        }
    }

    {
        int lo = min(b1i0, b2i0), hi = max(b1i0, b2i0);
        adj[(b * 64 + lo) * 64 + hi] = 1;
    }
    {
        int lo = min(b1i1, b2i1), hi = max(b1i1, b2i1);
        adj[(b * 64 + lo) * 64 + hi] = 1;
    }
}

__global__ void __launch_bounds__(64)
finalize_kernel(const unsigned char* __restrict__ adj, float* __restrict__ out)
{
    const int b = blockIdx.x;
    const int t = threadIdx.x;
    __shared__ int labels[64];

    unsigned long long m = 0ull;
    for (int j = 0; j < 64; ++j) {
        if (adj[(b * 64 + t) * 64 + j] | adj[(b * 64 + j) * 64 + t])
            m |= (1ull << j);
    }
    labels[t] = t;
    __syncthreads();

    for (int it = 0; it < 64; ++it) {
        int mn = labels[t];
        unsigned long long mm = m;
        while (mm) {
            int j = __ffsll(mm) - 1;
            int lj = labels[j];
            mn = mn < lj ? mn : lj;
            mm &= mm - 1;
        }
        __syncthreads();
        labels[t] = mn;
        __syncthreads();
    }

    unsigned long long hi_mask = (t < 63) ? (~0ull << (t + 1)) : 0ull;
    int myedges = __popcll(m & hi_mask);
    int mycomp  = (labels[t] == t) ? 1 : 0;

    for (int off = 32; off >= 1; off >>= 1) {
        myedges += __shfl_down(myedges, off);
        mycomp  += __shfl_down(mycomp, off);
    }
    if (t == 0) {
        float beta0 = (float)mycomp;
        float beta1 = (float)(myedges - (64 - mycomp));
        out[b]      = beta0;
        out[8 + b]  = beta1;
        out[16 + b] = beta0 / 64.f;
        out[24 + b] = (beta1 > 3.f) ? 1.f : 0.f;
    }
}

// ---------------------------------------------------------------------------
extern "C" void kernel_launch(void* const* d_in, const int* in_sizes, int n_in,
                              void* d_out, int out_size, void* d_ws, size_t ws_size,
                              hipStream_t stream)
{
    const float* emb = (const float*)d_in[0];
    const float* cs  = (const float*)d_in[1];
    float* out = (float*)d_out;

    char* ws = (char*)d_ws;
    float*              xn   = (float*)(ws);                       // 524288 B
    unsigned long long* slot = (unsigned long long*)(ws + 524288); // 4096 B
    unsigned long long* flg  = (unsigned long long*)(ws + 528384); // 4096 B
    unsigned int*       cnt  = (unsigned int*)(ws + 532480);       // 4096 B
    unsigned int*       gadj = (unsigned int*)(ws + 536576);       // 4096 B
    // fallback scratch
    int*           lmi  = (int*)  (ws + 540672);                   // 4096 B
    float*         pval = (float*)(ws + 544768);                   // 4096 B
    int*           pidx = (int*)  (ws + 548864);                   // 4096 B
    unsigned char* adjb = (unsigned char*)(ws + 552960);           // 32768 B

    int nb = 0;
    hipError_t qe = hipOccupancyMaxActiveBlocksPerMultiprocessor(
        &nb, fps_all_kernel, TPB, 0);
    const bool use_fused = (qe == hipSuccess && nb >= 1);

    if (use_fused) {
        hipLaunchKernelGGL(init_kernel, dim3(1), dim3(1024), 0, stream,
                           (unsigned int*)(ws + 524288));
        void* args[] = { (void*)&emb, (void*)&cs, (void*)&xn,
                         (void*)&slot, (void*)&flg, (void*)&cnt,
                         (void*)&gadj, (void*)&out };
        hipLaunchCooperativeKernel((void*)fps_all_kernel, dim3(256), dim3(TPB),
                                   args, 0, stream);
    } else {
        void* args[] = { (void*)&emb, (void*)&cs, (void*)&xn, (void*)&lmi,
                         (void*)&pval, (void*)&pidx, (void*)&adjb };
        hipLaunchCooperativeKernel((void*)fps_kernel, dim3(512), dim3(256),
                                   args, 0, stream);
        hipLaunchKernelGGL(witness_kernel, dim3(B_ * 32), dim3(256), 0, stream,
                           emb, cs, xn, lmi, adjb);
        hipLaunchKernelGGL(finalize_kernel, dim3(B_), dim3(64), 0, stream,
                           adjb, out);
    }
}

// Round 5
// 877.778 us; speedup vs baseline: 5.9263x; 5.9113x over previous
//
#include <hip/hip_runtime.h>

static constexpr int B_ = 8;
static constexpr int N_ = 16384;
static constexpr int D_ = 256;
static constexpr int L_ = 64;

static constexpr int TPB = 512;       // 256 WGs x 512 thr, 1 WG/CU (LDS-forced), 1 point/thread
static constexpr int LF4 = 16;        // dims 0..63 in LDS
static constexpr int RF4 = 48;        // dims 64..255 in VGPRs

// ws layout (init zeroes the first 204800 B every call; ws poisoned 0xAA once):
//   slot  u64[8][64][32]  @ 0       (131072 B)  packed (val,~n) per WG per step
//   xslot u32[8][64][32]  @ 131072  ( 65536 B)  xn of that WG's candidate
//   gadj  u32[8][128]     @ 196608  (  4096 B)  64x64 edge bitmask per batch
//   cnt   u32[8]          @ 200704  (   256 B)  final arrival counters

__global__ void __launch_bounds__(1024)
init_kernel(unsigned int* __restrict__ z)
{
    z[blockIdx.x * 1024 + threadIdx.x] = 0u;   // grid 50 -> 51200 words = 204800 B
}

// ---------------------------------------------------------------------------
// Fused FPS scan + witness + finalize. REGULAR launch (no coop, no grid.sync).
// Per-batch single-phase barrier per step: each WG release-stores its packed
// candidate into slot[b][s][wib]; wave 0 spins on agent-scope LOADS of all 32
// slots (valid keys >= 2^32, zero = not ready), max-reduces -> winner.
// All compare/FMA orders bit-identical to the r4-validated kernel.
// ---------------------------------------------------------------------------
__global__ void __launch_bounds__(TPB, 2)
fps_all_kernel(const float* __restrict__ emb, const float* __restrict__ csp,
               unsigned long long* __restrict__ slot,
               unsigned int* __restrict__ xslot,
               unsigned int* __restrict__ gadj,
               unsigned int* __restrict__ cnt,
               float* __restrict__ out)
{
    const int wg  = blockIdx.x;        // 0..255
    const int b   = wg >> 5;           // batch (32 WGs/batch)
    const int wib = wg & 31;
    const int tid = threadIdx.x;
    const int n   = (wib << 9) + tid;  // my point
    const float c = fabsf(csp[0]);

    __shared__ float4 slab[LF4 * TPB];          // 128 KB resident slice
    __shared__ __align__(16) float lmbuf[D_];   // staged landmark row
    __shared__ float wval[8];
    __shared__ int   widx[8];
    __shared__ float wxn[8];
    __shared__ int   s_next;
    __shared__ float s_lmn;
    __shared__ int   s_lead;
    __shared__ unsigned int lmask[128];         // 64x64 edge bitmask
    __shared__ int   labels[64];

    if (tid < 128) lmask[tid] = 0u;

    const float4* __restrict__ pt = (const float4*)(emb + (size_t)(b * N_ + n) * D_);

    // resident load + norm (sequential 4-acc over k=0..63, matches r1/r3/r4)
    float4 p[RF4];
    float s0 = 0.f, s1 = 0.f, s2 = 0.f, s3 = 0.f;
    #pragma unroll
    for (int k = 0; k < LF4; ++k) {
        float4 v = pt[k];
        slab[k * TPB + tid] = v;
        s0 = fmaf(v.x, v.x, s0); s1 = fmaf(v.y, v.y, s1);
        s2 = fmaf(v.z, v.z, s2); s3 = fmaf(v.w, v.w, s3);
    }
    #pragma unroll
    for (int k = 0; k < RF4; ++k) {
        float4 v = pt[LF4 + k];
        p[k] = v;
        s0 = fmaf(v.x, v.x, s0); s1 = fmaf(v.y, v.y, s1);
        s2 = fmaf(v.z, v.z, s2); s3 = fmaf(v.w, v.w, s3);
    }
    const float my_xn = (s0 + s1) + (s2 + s3);

    float min_d = __builtin_inff();
    float b1v = __builtin_inff(), b2v = __builtin_inff();
    int   b1i = 0, b2i = 0;
    int   lm = 0;
    float lmn_c = 0.f;

    #pragma unroll 1
    for (int s = 1; s <= L_; ++s) {
        // stage row of landmark position s-1 (index lm)
        if (tid < 64)
            ((float4*)lmbuf)[tid] =
                ((const float4*)(emb + (size_t)(b * N_ + lm) * D_))[tid];
        __syncthreads();

        float lmn;
        if (s == 1) {
            // landmark 0's norm computed locally (same op order as r4)
            const float4* l4 = (const float4*)lmbuf;
            float t0 = 0.f, t1 = 0.f, t2 = 0.f, t3 = 0.f;
            #pragma unroll
            for (int k = 0; k < 64; ++k) {
                float4 w = l4[k];
                t0 = fmaf(w.x, w.x, t0); t1 = fmaf(w.y, w.y, t1);
                t2 = fmaf(w.z, w.z, t2); t3 = fmaf(w.w, w.w, t3);
            }
            lmn = (t0 + t1) + (t2 + t3);
        } else {
            lmn = lmn_c;   // winner's xn from previous barrier
        }

        const float4* __restrict__ w4 = (const float4*)lmbuf;
        float d0 = 0.f, d1 = 0.f, d2 = 0.f, d3 = 0.f;
        #pragma unroll
        for (int k = 0; k < LF4; ++k) {
            float4 v = slab[k * TPB + tid];
            float4 w = w4[k];
            d0 = fmaf(v.x, w.x, d0); d1 = fmaf(v.y, w.y, d1);
            d2 = fmaf(v.z, w.z, d2); d3 = fmaf(v.w, w.w, d3);
        }
        #pragma unroll
        for (int k = 0; k < RF4; ++k) {
            float4 v = p[k];
            float4 w = w4[LF4 + k];
            d0 = fmaf(v.x, w.x, d0); d1 = fmaf(v.y, w.y, d1);
            d2 = fmaf(v.z, w.z, d2); d3 = fmaf(v.w, w.w, d3);
        }
        const float dot  = (d0 + d1) + (d2 + d3);
        const float diff = fmaxf(my_xn + lmn - 2.f * dot, 1e-10f);
        const float fac  = fmaxf(1.f + c * my_xn + c * lmn, 1e-6f);
        const float d    = sqrtf(diff) * sqrtf(fac);

        // fused witness: landmark POSITION s-1, ascending order, strict '<'
        if (d < b1v)      { b2v = b1v; b2i = b1i; b1v = d; b1i = s - 1; }
        else if (d < b2v) { b2v = d; b2i = s - 1; }

        if (s == L_) break;

        min_d = fminf(min_d, d);

        // wave argmax (tie -> lower n), carrying the candidate's xn
        float v = min_d; int i = n; float x = my_xn;
        #pragma unroll
        for (int off = 32; off >= 1; off >>= 1) {
            float ov = __shfl_down(v, off);
            int   oi = __shfl_down(i, off);
            float ox = __shfl_down(x, off);
            if (ov > v || (ov == v && oi < i)) { v = ov; i = oi; x = ox; }
        }
        if ((tid & 63) == 0) {
            const int w = tid >> 6;
            wval[w] = v; widx[w] = i; wxn[w] = x;
        }
        __syncthreads();

        if (tid < 64) {   // wave 0: publish, spin, reduce, broadcast
            v = (tid < 8) ? wval[tid] : -__builtin_inff();
            i = (tid < 8) ? widx[tid] : 0x7FFFFFFF;
            x = (tid < 8) ? wxn[tid]  : 0.f;
            #pragma unroll
            for (int off = 4; off >= 1; off >>= 1) {
                float ov = __shfl_down(v, off);
                int   oi = __shfl_down(i, off);
                float ox = __shfl_down(x, off);
                if (ov > v || (ov == v && oi < i)) { v = ov; i = oi; x = ox; }
            }
            const int base = (b * 64 + s) * 32;
            if (tid == 0) {
                const unsigned long long key =
                    ((unsigned long long)__float_as_uint(v) << 32) |
                    (unsigned long long)(0xFFFFFFFFu - (unsigned)i);
                __hip_atomic_store(&xslot[base + wib], __float_as_uint(x),
                                   __ATOMIC_RELAXED, __HIP_MEMORY_SCOPE_AGENT);
                __hip_atomic_store(&slot[base + wib], key,
                                   __ATOMIC_RELEASE, __HIP_MEMORY_SCOPE_AGENT);
            }
            // spin on plain agent-scope loads (no RMW serialization)
            unsigned long long myk;
            for (;;) {
                myk = __hip_atomic_load(&slot[base + (tid & 31)],
                                        __ATOMIC_RELAXED, __HIP_MEMORY_SCOPE_AGENT);
                if (__all(myk != 0ull)) break;
                __builtin_amdgcn_s_sleep(1);
            }
            __builtin_amdgcn_fence(__ATOMIC_ACQUIRE, "agent");
            // max-reduce 32 distinct keys (lanes 32..63 are duplicates)
            unsigned long long k = myk;
            #pragma unroll
            for (int off = 32; off >= 1; off >>= 1) {
                unsigned long long ok = __shfl_down(k, off);
                if (ok > k) k = ok;
            }
            if (tid == 0) {
                const unsigned wn = 0xFFFFFFFFu - (unsigned)(k & 0xFFFFFFFFull);
                s_next = (int)wn;
                s_lmn  = __uint_as_float(
                    __hip_atomic_load(&xslot[base + (wn >> 9)],
                                      __ATOMIC_RELAXED, __HIP_MEMORY_SCOPE_AGENT));
            }
        }
        __syncthreads();
        lm    = s_next;
        lmn_c = s_lmn;
    }

    // emit my edge (top-2 landmark positions) into LDS bitmask
    {
        const int lo = min(b1i, b2i), hi = max(b1i, b2i);
        const int bitpos = lo * 64 + hi;
        atomicOr(&lmask[bitpos >> 5], 1u << (bitpos & 31));
    }
    __syncthreads();
    if (tid < 128) {
        unsigned w = lmask[tid];
        if (w) atomicOr(&gadj[b * 128 + tid], w);   // device-scope RMW at LLC
    }
    __syncthreads();

    if (tid == 0) {
        __threadfence();
        unsigned prev = atomicAdd(&cnt[b], 1u);
        s_lead = (prev == 31u) ? 1 : 0;
    }
    __syncthreads();
    if (!s_lead) return;

    // ---- leader WG (last arriver): finalize this batch ----
    __threadfence();
    if (tid < 128) lmask[tid] = atomicOr(&gadj[b * 128 + tid], 0u);  // coherent read
    __syncthreads();

    unsigned long long m = 0ull;
    if (tid < 64) {
        m = ((unsigned long long)lmask[tid * 2 + 1] << 32) | lmask[tid * 2];
        for (int j = 0; j < 64; ++j)           // symmetrize: column bits
            if (lmask[j * 2 + (tid >> 5)] & (1u << (tid & 31))) m |= 1ull << j;
        labels[tid] = tid;
    }
    __syncthreads();

    for (int it = 0; it < 64; ++it) {          // synchronous min-label propagation
        int mn = 0;
        if (tid < 64) {
            mn = labels[tid];
            unsigned long long mm = m;
            while (mm) {
                int j = __ffsll(mm) - 1;
                int lj = labels[j];
                mn = mn < lj ? mn : lj;
                mm &= mm - 1;
            }
        }
        __syncthreads();
        if (tid < 64) labels[tid] = mn;
        __syncthreads();
    }

    if (tid < 64) {
        unsigned long long hi_mask = (tid < 63) ? (~0ull << (tid + 1)) : 0ull;
        int myedges = __popcll(m & hi_mask);
        int mycomp  = (labels[tid] == tid) ? 1 : 0;
        #pragma unroll
        for (int off = 32; off >= 1; off >>= 1) {
            myedges += __shfl_down(myedges, off);
            mycomp  += __shfl_down(mycomp, off);
        }
        if (tid == 0) {
            float beta0 = (float)mycomp;
            float beta1 = (float)(myedges - (64 - mycomp));
            out[b]      = beta0;
            out[8 + b]  = beta1;
            out[16 + b] = beta0 / 64.f;
            out[24 + b] = (beta1 > 3.f) ? 1.f : 0.f;
        }
    }
}

// ---------------------------------------------------------------------------
extern "C" void kernel_launch(void* const* d_in, const int* in_sizes, int n_in,
                              void* d_out, int out_size, void* d_ws, size_t ws_size,
                              hipStream_t stream)
{
    const float* emb = (const float*)d_in[0];
    const float* cs  = (const float*)d_in[1];
    float* out = (float*)d_out;

    char* ws = (char*)d_ws;
    unsigned long long* slot  = (unsigned long long*)(ws);
    unsigned int*       xslot = (unsigned int*)(ws + 131072);
    unsigned int*       gadj  = (unsigned int*)(ws + 196608);
    unsigned int*       cnt   = (unsigned int*)(ws + 200704);

    hipLaunchKernelGGL(init_kernel, dim3(50), dim3(1024), 0, stream,
                       (unsigned int*)ws);
    hipLaunchKernelGGL(fps_all_kernel, dim3(256), dim3(TPB), 0, stream,
                       emb, cs, slot, xslot, gadj, cnt, out);
}

// Round 6
// 766.346 us; speedup vs baseline: 6.7880x; 1.1454x over previous
//
#include <hip/hip_runtime.h>

static constexpr int B_ = 8;
static constexpr int N_ = 16384;
static constexpr int D_ = 256;
static constexpr int L_ = 64;

static constexpr int TPB = 512;       // 256 WGs x 512 thr, 1 WG/CU (LDS-forced), 1 point/thread
static constexpr int LF4 = 18;        // dims 0..71 in LDS (18 float4/thread)
static constexpr int RF4 = 64 - LF4;  // dims 72..255 in VGPRs (46 float4 = 184 VGPRs)

// ws layout (init zeroes the first 135424 B every call; ws poisoned 0xAA once):
//   slot  u64[8][64][32]  @ 0       (131072 B)  packed (val,~n) per WG per step
//   gadj  u32[8][128]     @ 131072  (  4096 B)  64x64 edge bitmask per batch
//   cnt   u32[8]          @ 135168  (   256 B)  finalize arrival counters

__global__ void __launch_bounds__(1024)
init_kernel(unsigned int* __restrict__ z)
{
    z[blockIdx.x * 1024 + threadIdx.x] = 0u;   // grid 34 -> 34816 words = 139264 B
}

// ---------------------------------------------------------------------------
// Fused FPS scan + witness + finalize. Regular launch, fence-free per-batch
// barrier: each WG publishes its step candidate with ONE relaxed agent-scope
// atomic store; wave 0 spins on relaxed atomic loads of all 32 slots (valid
// keys != 0), max-reduces in-wave -> winner. The landmark's norm is
// recomputed locally from the staged row (identical op order -> bit-identical
// to the r5-validated carried value), so no other cross-WG data exists and
// no fences are needed (emb is read-only).
// ---------------------------------------------------------------------------
__global__ void __launch_bounds__(TPB, 1)
fps_all_kernel(const float* __restrict__ emb, const float* __restrict__ csp,
               unsigned long long* __restrict__ slot,
               unsigned int* __restrict__ gadj,
               unsigned int* __restrict__ cnt,
               float* __restrict__ out)
{
    const int wg  = blockIdx.x;        // 0..255
    const int b   = wg >> 5;           // batch (32 WGs/batch)
    const int wib = wg & 31;
    const int tid = threadIdx.x;
    const int n   = (wib << 9) + tid;  // my point
    const float c = fabsf(csp[0]);

    __shared__ float4 slab[LF4 * TPB];          // 147456 B resident slice
    __shared__ __align__(16) float lmbuf[D_];   // staged landmark row
    __shared__ float wval[8];
    __shared__ int   widx[8];
    __shared__ int   s_next;
    __shared__ int   s_lead;
    __shared__ unsigned int lmask[128];         // 64x64 edge bitmask
    __shared__ int   labels[64];

    if (tid < 128) lmask[tid] = 0u;

    const float4* __restrict__ pt = (const float4*)(emb + (size_t)(b * N_ + n) * D_);

    // resident load + norm (sequential 4-acc over k=0..63, matches r1..r5)
    float4 p[RF4];
    float s0 = 0.f, s1 = 0.f, s2 = 0.f, s3 = 0.f;
    #pragma unroll
    for (int k = 0; k < LF4; ++k) {
        float4 v = pt[k];
        slab[k * TPB + tid] = v;
        s0 = fmaf(v.x, v.x, s0); s1 = fmaf(v.y, v.y, s1);
        s2 = fmaf(v.z, v.z, s2); s3 = fmaf(v.w, v.w, s3);
    }
    #pragma unroll
    for (int k = 0; k < RF4; ++k) {
        float4 v = pt[LF4 + k];
        p[k] = v;
        s0 = fmaf(v.x, v.x, s0); s1 = fmaf(v.y, v.y, s1);
        s2 = fmaf(v.z, v.z, s2); s3 = fmaf(v.w, v.w, s3);
    }
    const float my_xn = (s0 + s1) + (s2 + s3);

    float min_d = __builtin_inff();
    float b1v = __builtin_inff(), b2v = __builtin_inff();
    int   b1i = 0, b2i = 0;
    int   lm = 0;

    #pragma unroll 1
    for (int s = 1; s <= L_; ++s) {
        // stage row of landmark position s-1 (index lm); wave 0 loads 1 KB
        if (tid < 64)
            ((float4*)lmbuf)[tid] =
                ((const float4*)(emb + (size_t)(b * N_ + lm) * D_))[tid];
        __syncthreads();

        // landmark norm recomputed locally (same 4-acc k-ascending order ->
        // bit-identical to the per-point norms of the validated kernels)
        const float4* __restrict__ w4 = (const float4*)lmbuf;
        float t0 = 0.f, t1 = 0.f, t2 = 0.f, t3 = 0.f;
        #pragma unroll
        for (int k = 0; k < 64; ++k) {
            float4 w = w4[k];
            t0 = fmaf(w.x, w.x, t0); t1 = fmaf(w.y, w.y, t1);
            t2 = fmaf(w.z, w.z, t2); t3 = fmaf(w.w, w.w, t3);
        }
        const float lmn = (t0 + t1) + (t2 + t3);

        float d0 = 0.f, d1 = 0.f, d2 = 0.f, d3 = 0.f;
        #pragma unroll
        for (int k = 0; k < LF4; ++k) {
            float4 v = slab[k * TPB + tid];
            float4 w = w4[k];
            d0 = fmaf(v.x, w.x, d0); d1 = fmaf(v.y, w.y, d1);
            d2 = fmaf(v.z, w.z, d2); d3 = fmaf(v.w, w.w, d3);
        }
        #pragma unroll
        for (int k = 0; k < RF4; ++k) {
            float4 v = p[k];
            float4 w = w4[LF4 + k];
            d0 = fmaf(v.x, w.x, d0); d1 = fmaf(v.y, w.y, d1);
            d2 = fmaf(v.z, w.z, d2); d3 = fmaf(v.w, w.w, d3);
        }
        const float dot  = (d0 + d1) + (d2 + d3);
        const float diff = fmaxf(my_xn + lmn - 2.f * dot, 1e-10f);
        const float fac  = fmaxf(1.f + c * my_xn + c * lmn, 1e-6f);
        const float d    = sqrtf(diff) * sqrtf(fac);

        // fused witness: landmark POSITION s-1, ascending order, strict '<'
        if (d < b1v)      { b2v = b1v; b2i = b1i; b1v = d; b1i = s - 1; }
        else if (d < b2v) { b2v = d; b2i = s - 1; }

        if (s == L_) break;

        min_d = fminf(min_d, d);

        // wave argmax (tie -> lower n)
        float v = min_d; int i = n;
        #pragma unroll
        for (int off = 32; off >= 1; off >>= 1) {
            float ov = __shfl_down(v, off);
            int   oi = __shfl_down(i, off);
            if (ov > v || (ov == v && oi < i)) { v = ov; i = oi; }
        }
        if ((tid & 63) == 0) { wval[tid >> 6] = v; widx[tid >> 6] = i; }
        __syncthreads();

        if (tid < 64) {   // wave 0: publish, spin, reduce, broadcast
            v = (tid < 8) ? wval[tid] : -__builtin_inff();
            i = (tid < 8) ? widx[tid] : 0x7FFFFFFF;
            #pragma unroll
            for (int off = 4; off >= 1; off >>= 1) {
                float ov = __shfl_down(v, off);
                int   oi = __shfl_down(i, off);
                if (ov > v || (ov == v && oi < i)) { v = ov; i = oi; }
            }
            const int base = (b * 64 + s) * 32;
            if (tid == 0) {
                const unsigned long long key =
                    ((unsigned long long)__float_as_uint(v) << 32) |
                    (unsigned long long)(0xFFFFFFFFu - (unsigned)i);
                __hip_atomic_store(&slot[base + wib], key,
                                   __ATOMIC_RELAXED, __HIP_MEMORY_SCOPE_AGENT);
            }
            // fence-free spin on relaxed agent-scope loads
            unsigned long long myk;
            for (;;) {
                myk = __hip_atomic_load(&slot[base + (tid & 31)],
                                        __ATOMIC_RELAXED, __HIP_MEMORY_SCOPE_AGENT);
                if (__all(myk != 0ull)) break;
                __builtin_amdgcn_s_sleep(1);
            }
            // max-reduce 32 distinct keys (lanes 32..63 are duplicates)
            unsigned long long k = myk;
            #pragma unroll
            for (int off = 32; off >= 1; off >>= 1) {
                unsigned long long ok = __shfl_down(k, off);
                if (ok > k) k = ok;
            }
            if (tid == 0)
                s_next = (int)(0xFFFFFFFFu - (unsigned)(k & 0xFFFFFFFFull));
        }
        __syncthreads();
        lm = s_next;
    }

    // emit my edge (top-2 landmark positions) into LDS bitmask
    {
        const int lo = min(b1i, b2i), hi = max(b1i, b2i);
        const int bitpos = lo * 64 + hi;
        atomicOr(&lmask[bitpos >> 5], 1u << (bitpos & 31));
    }
    __syncthreads();
    if (tid < 128) {
        unsigned w = lmask[tid];
        if (w) atomicOr(&gadj[b * 128 + tid], w);   // device-scope RMW at LLC
    }
    __syncthreads();

    if (tid == 0) {
        __threadfence();
        unsigned prev = atomicAdd(&cnt[b], 1u);
        s_lead = (prev == 31u) ? 1 : 0;
    }
    __syncthreads();
    if (!s_lead) return;

    // ---- leader WG (last arriver): finalize this batch ----
    __threadfence();
    if (tid < 128) lmask[tid] = atomicOr(&gadj[b * 128 + tid], 0u);  // coherent read
    __syncthreads();

    unsigned long long m = 0ull;
    if (tid < 64) {
        m = ((unsigned long long)lmask[tid * 2 + 1] << 32) | lmask[tid * 2];
        for (int j = 0; j < 64; ++j)           // symmetrize: column bits
            if (lmask[j * 2 + (tid >> 5)] & (1u << (tid & 31))) m |= 1ull << j;
        labels[tid] = tid;
    }
    __syncthreads();

    for (int it = 0; it < 64; ++it) {          // synchronous min-label propagation
        int mn = 0;
        if (tid < 64) {
            mn = labels[tid];
            unsigned long long mm = m;
            while (mm) {
                int j = __ffsll(mm) - 1;
                int lj = labels[j];
                mn = mn < lj ? mn : lj;
                mm &= mm - 1;
            }
        }
        __syncthreads();
        if (tid < 64) labels[tid] = mn;
        __syncthreads();
    }

    if (tid < 64) {
        unsigned long long hi_mask = (tid < 63) ? (~0ull << (tid + 1)) : 0ull;
        int myedges = __popcll(m & hi_mask);
        int mycomp  = (labels[tid] == tid) ? 1 : 0;
        #pragma unroll
        for (int off = 32; off >= 1; off >>= 1) {
            myedges += __shfl_down(myedges, off);
            mycomp  += __shfl_down(mycomp, off);
        }
        if (tid == 0) {
            float beta0 = (float)mycomp;
            float beta1 = (float)(myedges - (64 - mycomp));
            out[b]      = beta0;
            out[8 + b]  = beta1;
            out[16 + b] = beta0 / 64.f;
            out[24 + b] = (beta1 > 3.f) ? 1.f : 0.f;
        }
    }
}

// ---------------------------------------------------------------------------
extern "C" void kernel_launch(void* const* d_in, const int* in_sizes, int n_in,
                              void* d_out, int out_size, void* d_ws, size_t ws_size,
                              hipStream_t stream)
{
    const float* emb = (const float*)d_in[0];
    const float* cs  = (const float*)d_in[1];
    float* out = (float*)d_out;

    char* ws = (char*)d_ws;
    unsigned long long* slot = (unsigned long long*)(ws);
    unsigned int*       gadj = (unsigned int*)(ws + 131072);
    unsigned int*       cnt  = (unsigned int*)(ws + 135168);

    hipLaunchKernelGGL(init_kernel, dim3(34), dim3(1024), 0, stream,
                       (unsigned int*)ws);
    hipLaunchKernelGGL(fps_all_kernel, dim3(256), dim3(TPB), 0, stream,
                       emb, cs, slot, gadj, cnt, out);
}

// Round 8
// 744.158 us; speedup vs baseline: 6.9904x; 1.0298x over previous
//
#include <hip/hip_runtime.h>

static constexpr int B_ = 8;
static constexpr int N_ = 16384;
static constexpr int D_ = 256;
static constexpr int L_ = 64;

static constexpr int TPB = 512;       // 256 WGs x 512 thr, 1 WG/CU (LDS-forced), 1 point/thread
static constexpr int LF4 = 18;        // dims 0..71 in LDS
static constexpr int RF4 = 64 - LF4;  // dims 72..255 in VGPRs (46 float4 = 184 regs)

// ws layout (init zeroes 204800 B every call; ws poisoned 0xAA once):
//   slot u64[8][64][32] @ 0       (131072 B)  packed (val_bits<<32)|(~n) per WG per step
//   pay  u32[8][64][32] @ 131072  ( 65536 B)  xn_bits^0x80000000 of that candidate
//   gadj u32[8][128]    @ 196608  (  4096 B)  64x64 edge bitmask per batch
//   cnt  u32[8]         @ 200704  (    32 B)  finalize arrival counters

__global__ void __launch_bounds__(1024)
init_kernel(unsigned int* __restrict__ z)
{
    z[blockIdx.x * 1024 + threadIdx.x] = 0u;   // grid 50 -> 204800 B
}

// ---------------------------------------------------------------------------
// Fused FPS scan + witness + finalize. Regular launch; r6-proven LLC barrier
// (relaxed agent-scope atomics only — no fences, no sc0 games):
//   publish: store pay (enc norm), s_waitcnt vmcnt(0), store slot (key).
//   poll:    each lane relaxed-loads (key, enc) of one WG; retry until ALL
//            keys and encs nonzero (stale zeros -> benign retry);
//            max-reduce keys carrying enc -> winner index + winner norm.
// Register budget pinned to 256 VGPRs (2 waves/EU) so p[] never spills.
// All FMA/compare orders bit-identical to the r5/r6-validated kernels.
// ---------------------------------------------------------------------------
__global__ __attribute__((amdgpu_flat_work_group_size(512, 512),
                          amdgpu_waves_per_eu(2, 2)))
void fps_all_kernel(const float* __restrict__ emb, const float* __restrict__ csp,
                    unsigned long long* __restrict__ slot,
                    unsigned int* __restrict__ pay,
                    unsigned int* __restrict__ gadj,
                    unsigned int* __restrict__ cnt,
                    float* __restrict__ out)
{
    const int wg  = blockIdx.x;        // 0..255
    const int b   = wg >> 5;           // batch (32 WGs/batch)
    const int wib = wg & 31;
    const int tid = threadIdx.x;
    const int n   = (wib << 9) + tid;  // my point
    const float c = fabsf(csp[0]);

    __shared__ float4 slab[LF4 * TPB];          // 147456 B resident slice
    __shared__ __align__(16) float lmbuf[D_];
    __shared__ float wval[8];
    __shared__ int   widx[8];
    __shared__ float wxn[8];
    __shared__ int   s_next;
    __shared__ float s_lmn;
    __shared__ int   s_lead;
    __shared__ unsigned int lmask[128];
    __shared__ int   labels[64];

    if (tid < 128) lmask[tid] = 0u;

    const float4* __restrict__ pt = (const float4*)(emb + (size_t)(b * N_ + n) * D_);

    // resident load + norm (sequential 4-acc over k=0..63, matches r1..r6)
    float4 p[RF4];
    float s0 = 0.f, s1 = 0.f, s2 = 0.f, s3 = 0.f;
    #pragma unroll
    for (int k = 0; k < LF4; ++k) {
        float4 v = pt[k];
        slab[k * TPB + tid] = v;
        s0 = fmaf(v.x, v.x, s0); s1 = fmaf(v.y, v.y, s1);
        s2 = fmaf(v.z, v.z, s2); s3 = fmaf(v.w, v.w, s3);
    }
    #pragma unroll
    for (int k = 0; k < RF4; ++k) {
        float4 v = pt[LF4 + k];
        p[k] = v;
        s0 = fmaf(v.x, v.x, s0); s1 = fmaf(v.y, v.y, s1);
        s2 = fmaf(v.z, v.z, s2); s3 = fmaf(v.w, v.w, s3);
    }
    const float my_xn = (s0 + s1) + (s2 + s3);

    float min_d = __builtin_inff();
    float b1v = __builtin_inff(), b2v = __builtin_inff();
    int   b1i = 0, b2i = 0;
    int   lm    = 0;      // landmark 0 = point 0
    float lmn_c = 0.f;    // carried winner norm (valid from s>=2)

    #pragma unroll 1
    for (int s = 1; s <= L_; ++s) {
        // stage row of landmark position s-1 (index lm)
        if (tid < 64)
            ((float4*)lmbuf)[tid] =
                ((const float4*)(emb + (size_t)(b * N_ + lm) * D_))[tid];
        __syncthreads();

        float lmn;
        if (s == 1) {
            // landmark 0's norm computed locally (r6-validated, same op order)
            const float4* l4 = (const float4*)lmbuf;
            float t0 = 0.f, t1 = 0.f, t2 = 0.f, t3 = 0.f;
            #pragma unroll
            for (int k = 0; k < 64; ++k) {
                float4 w = l4[k];
                t0 = fmaf(w.x, w.x, t0); t1 = fmaf(w.y, w.y, t1);
                t2 = fmaf(w.z, w.z, t2); t3 = fmaf(w.w, w.w, t3);
            }
            lmn = (t0 + t1) + (t2 + t3);
        } else {
            lmn = lmn_c;   // winner's xn carried through the barrier (r5-validated)
        }

        const float4* __restrict__ w4 = (const float4*)lmbuf;
        float d0 = 0.f, d1 = 0.f, d2 = 0.f, d3 = 0.f;
        #pragma unroll
        for (int k = 0; k < LF4; ++k) {
            float4 v = slab[k * TPB + tid];
            float4 w = w4[k];
            d0 = fmaf(v.x, w.x, d0); d1 = fmaf(v.y, w.y, d1);
            d2 = fmaf(v.z, w.z, d2); d3 = fmaf(v.w, w.w, d3);
        }
        #pragma unroll
        for (int k = 0; k < RF4; ++k) {
            float4 v = p[k];
            float4 w = w4[LF4 + k];
            d0 = fmaf(v.x, w.x, d0); d1 = fmaf(v.y, w.y, d1);
            d2 = fmaf(v.z, w.z, d2); d3 = fmaf(v.w, w.w, d3);
        }
        const float dot  = (d0 + d1) + (d2 + d3);
        const float diff = fmaxf(my_xn + lmn - 2.f * dot, 1e-10f);
        const float fac  = fmaxf(1.f + c * my_xn + c * lmn, 1e-6f);
        const float d    = sqrtf(diff) * sqrtf(fac);

        // fused witness: landmark POSITION s-1, ascending order, strict '<'
        if (d < b1v)      { b2v = b1v; b2i = b1i; b1v = d; b1i = s - 1; }
        else if (d < b2v) { b2v = d; b2i = s - 1; }

        if (s == L_) break;

        min_d = fminf(min_d, d);

        // wave argmax (tie -> lower n), carrying candidate's xn
        float v = min_d; int i = n; float x = my_xn;
        #pragma unroll
        for (int off = 32; off >= 1; off >>= 1) {
            float ov = __shfl_down(v, off);
            int   oi = __shfl_down(i, off);
            float ox = __shfl_down(x, off);
            if (ov > v || (ov == v && oi < i)) { v = ov; i = oi; x = ox; }
        }
        if ((tid & 63) == 0) {
            const int w = tid >> 6;
            wval[w] = v; widx[w] = i; wxn[w] = x;
        }
        __syncthreads();

        if (tid < 64) {   // wave 0: publish, poll, reduce, broadcast
            v = (tid < 8) ? wval[tid] : -__builtin_inff();
            i = (tid < 8) ? widx[tid] : 0x7FFFFFFF;
            x = (tid < 8) ? wxn[tid]  : 0.f;
            #pragma unroll
            for (int off = 4; off >= 1; off >>= 1) {
                float ov = __shfl_down(v, off);
                int   oi = __shfl_down(i, off);
                float ox = __shfl_down(x, off);
                if (ov > v || (ov == v && oi < i)) { v = ov; i = oi; x = ox; }
            }
            const int base = (b * 64 + s) * 32;
            if (tid == 0) {
                const unsigned long long key =
                    ((unsigned long long)__float_as_uint(v) << 32) |
                    (unsigned long long)(0xFFFFFFFFu - (unsigned)i);
                const unsigned enc = __float_as_uint(x) ^ 0x80000000u;  // never 0
                __hip_atomic_store(&pay[base + wib], enc,
                                   __ATOMIC_RELAXED, __HIP_MEMORY_SCOPE_AGENT);
                asm volatile("s_waitcnt vmcnt(0)" ::: "memory");  // order enc before key
                __hip_atomic_store(&slot[base + wib], key,
                                   __ATOMIC_RELAXED, __HIP_MEMORY_SCOPE_AGENT);
            }
            // poll both words; stale zeros -> retry (no fences needed)
            unsigned long long myk; unsigned mye;
            for (;;) {
                myk = __hip_atomic_load(&slot[base + (tid & 31)],
                                        __ATOMIC_RELAXED, __HIP_MEMORY_SCOPE_AGENT);
                mye = __hip_atomic_load(&pay[base + (tid & 31)],
                                        __ATOMIC_RELAXED, __HIP_MEMORY_SCOPE_AGENT);
                if (__all((myk != 0ull) && (mye != 0u))) break;
                __builtin_amdgcn_s_sleep(1);
            }
            // max-reduce 32 distinct keys, carrying enc (lanes 32..63 duplicate)
            unsigned long long k = myk; unsigned e = mye;
            #pragma unroll
            for (int off = 32; off >= 1; off >>= 1) {
                unsigned long long ok = __shfl_down(k, off);
                unsigned           oe = __shfl_down(e, off);
                if (ok > k) { k = ok; e = oe; }
            }
            if (tid == 0) {
                s_next = (int)(0xFFFFFFFFu - (unsigned)(k & 0xFFFFFFFFull));
                s_lmn  = __uint_as_float(e ^ 0x80000000u);
            }
        }
        __syncthreads();
        lm    = s_next;
        lmn_c = s_lmn;
    }

    // emit my edge (top-2 landmark positions) into LDS bitmask
    {
        const int lo = min(b1i, b2i), hi = max(b1i, b2i);
        const int bitpos = lo * 64 + hi;
        atomicOr(&lmask[bitpos >> 5], 1u << (bitpos & 31));
    }
    __syncthreads();
    if (tid < 128) {
        unsigned w = lmask[tid];
        if (w) atomicOr(&gadj[b * 128 + tid], w);   // agent-scope RMW at LLC
    }
    __syncthreads();

    if (tid == 0) {
        __threadfence();
        unsigned prev = atomicAdd(&cnt[b], 1u);
        s_lead = (prev == 31u) ? 1 : 0;
    }
    __syncthreads();
    if (!s_lead) return;

    // ---- leader WG (last arriver): finalize this batch ----
    __threadfence();
    if (tid < 128) lmask[tid] = atomicOr(&gadj[b * 128 + tid], 0u);  // coherent read
    __syncthreads();

    unsigned long long m = 0ull;
    if (tid < 64) {
        m = ((unsigned long long)lmask[tid * 2 + 1] << 32) | lmask[tid * 2];
        for (int j = 0; j < 64; ++j)           // symmetrize: column bits
            if (lmask[j * 2 + (tid >> 5)] & (1u << (tid & 31))) m |= 1ull << j;
        labels[tid] = tid;
    }
    __syncthreads();

    for (int it = 0; it < 64; ++it) {          // synchronous min-label propagation
        int mn = 0;
        if (tid < 64) {
            mn = labels[tid];
            unsigned long long mm = m;
            while (mm) {
                int j = __ffsll(mm) - 1;
                int lj = labels[j];
                mn = mn < lj ? mn : lj;
                mm &= mm - 1;
            }
        }
        __syncthreads();
        if (tid < 64) labels[tid] = mn;
        __syncthreads();
    }

    if (tid < 64) {
        unsigned long long hi_mask = (tid < 63) ? (~0ull << (tid + 1)) : 0ull;
        int myedges = __popcll(m & hi_mask);
        int mycomp  = (labels[tid] == tid) ? 1 : 0;
        #pragma unroll
        for (int off = 32; off >= 1; off >>= 1) {
            myedges += __shfl_down(myedges, off);
            mycomp  += __shfl_down(mycomp, off);
        }
        if (tid == 0) {
            float beta0 = (float)mycomp;
            float beta1 = (float)(myedges - (64 - mycomp));
            out[b]      = beta0;
            out[8 + b]  = beta1;
            out[16 + b] = beta0 / 64.f;
            out[24 + b] = (beta1 > 3.f) ? 1.f : 0.f;
        }
    }
}

// ---------------------------------------------------------------------------
extern "C" void kernel_launch(void* const* d_in, const int* in_sizes, int n_in,
                              void* d_out, int out_size, void* d_ws, size_t ws_size,
                              hipStream_t stream)
{
    const float* emb = (const float*)d_in[0];
    const float* cs  = (const float*)d_in[1];
    float* out = (float*)d_out;

    char* ws = (char*)d_ws;
    unsigned long long* slot = (unsigned long long*)(ws);
    unsigned int*       pay  = (unsigned int*)(ws + 131072);
    unsigned int*       gadj = (unsigned int*)(ws + 196608);
    unsigned int*       cnt  = (unsigned int*)(ws + 200704);

    hipLaunchKernelGGL(init_kernel, dim3(50), dim3(1024), 0, stream,
                       (unsigned int*)ws);
    hipLaunchKernelGGL(fps_all_kernel, dim3(256), dim3(TPB), 0, stream,
                       emb, cs, slot, pay, gadj, cnt, out);
}